// Round 2
// baseline (356.149 us; speedup 1.0000x reference)
//
#include <hip/hip_runtime.h>
#include <math.h>

// Problem constants (from reference): B=4, CH=256, H=W=64, TOK=8, GCN=32,
// PAD=256, DIN=64, DSTATE=16, DTR=2, GROUPS=4.
#define TOKN 8
#define GCNN 32
#define DINN 64
#define DST 16
#define CHN 256
#define HWN 4096      // H*W
#define BBN 4
#define M_TOT 16384   // B*H*W
#define NSLOT 64      // contention-spreading slots per (b,group) stat

__device__ __forceinline__ float softplusf(float v) {
    // jax.nn.softplus = logaddexp(v, 0) = max(v,0) + log1p(exp(-|v|))
    return fmaxf(v, 0.f) + log1pf(expf(-fabsf(v)));
}
__device__ __forceinline__ float geluf(float v) {
    // exact gelu: 0.5*v*(1+erf(v/sqrt(2)))
    return 0.5f * v * (1.f + erff(v * 0.70710678118654752f));
}

struct PixSmem {
    float xf[256];          // [t*32+k] input tokens
    float xp[8][64];        // xz[...,:64]
    float zz[8][64];        // xz[...,64:]
    float dts[2][8][2];     // raw dt cols per direction
    float Bs[2][8][16];
    float Cs[2][8][16];
    float yscan[2][8][64];  // scan outputs (+ xs*Ds)
    float ycomb[8][64];     // (fwd + rev(bwd)) * gelu(z)
    float gsum[4];
    float gsq[4];
};

__global__ __launch_bounds__(256) void k1_scan(
    const float* __restrict__ x,
    const float* __restrict__ W_in,    // (32,128)
    const float* __restrict__ W_x,     // (64,34)
    const float* __restrict__ W_dt,    // (2,64)
    const float* __restrict__ b_dt,    // (64,)
    const float* __restrict__ A_logs,  // (64,16)
    const float* __restrict__ Ds,      // (64,)
    const float* __restrict__ W_out,   // (64,32)
    float* __restrict__ ws_y,          // (M,256) pre-GN output
    double* __restrict__ stats)        // (4,4,2,NSLOT)
{
    __shared__ PixSmem sm2[2];
    const int pix = threadIdx.x >> 7;
    const int lt  = threadIdx.x & 127;
    PixSmem& sm = sm2[pix];
    const int m  = blockIdx.x * 2 + pix;
    const int b  = m >> 12;
    const int hw = m & (HWN - 1);
    const float* xpix = x + (size_t)b * (CHN * HWN) + hw;

    // ---- phase 1: load the pixel's 256 channels; zero LDS stat accumulators
    if (lt < 4)      sm.gsum[lt] = 0.f;
    else if (lt < 8) sm.gsq[lt - 4] = 0.f;
    for (int c = lt; c < 256; c += 128)
        sm.xf[c] = xpix[(size_t)c * HWN];
    __syncthreads();

    // ---- phase 2: xz = xf @ W_in   (thread owns output column lt of 128)
    {
        float acc[8];
        #pragma unroll
        for (int t = 0; t < 8; ++t) acc[t] = 0.f;
        for (int k = 0; k < 32; ++k) {
            float wv = W_in[k * 128 + lt];
            #pragma unroll
            for (int t = 0; t < 8; ++t) acc[t] = fmaf(sm.xf[t * 32 + k], wv, acc[t]);
        }
        if (lt < 64) {
            #pragma unroll
            for (int t = 0; t < 8; ++t) sm.xp[t][lt] = acc[t];
        } else {
            #pragma unroll
            for (int t = 0; t < 8; ++t) sm.zz[t][lt - 64] = acc[t];
        }
    }
    __syncthreads();

    // ---- phase 3: x_dbl = xs @ W_x  (544 outputs: 2 dir x 8 t x 34 cols)
    for (int idx = lt; idx < 544; idx += 128) {
        int dir = idx / 272;
        int r   = idx - dir * 272;
        int t   = r / 34;
        int col = r - t * 34;
        int ts  = dir ? (7 - t) : t;   // xs backward = token-reversed xp
        float acc = 0.f;
        for (int k = 0; k < 64; ++k)
            acc = fmaf(sm.xp[ts][k], W_x[k * 34 + col], acc);
        if (col < 2)        sm.dts[dir][t][col] = acc;
        else if (col < 18)  sm.Bs[dir][t][col - 2] = acc;
        else                sm.Cs[dir][t][col - 18] = acc;
    }
    __syncthreads();

    // ---- phase 4: selective scan. thread = (dir, d); 16-state in registers
    {
        const int dir = lt >> 6;
        const int d   = lt & 63;
        float A[16];
        #pragma unroll
        for (int n = 0; n < 16; ++n) A[n] = -expf(A_logs[d * 16 + n]);
        const float w0  = W_dt[d];
        const float w1  = W_dt[64 + d];
        const float b2  = 2.f * b_dt[d];   // reference adds b_dt twice
        const float dsd = Ds[d];
        float h[16];
        #pragma unroll
        for (int n = 0; n < 16; ++n) h[n] = 0.f;
        for (int t = 0; t < 8; ++t) {
            int ts = dir ? (7 - t) : t;
            float u = sm.xp[ts][d];
            float delta = softplusf(fmaf(sm.dts[dir][t][0], w0,
                                    fmaf(sm.dts[dir][t][1], w1, b2)));
            float du = delta * u;
            float y = 0.f;
            #pragma unroll
            for (int n = 0; n < 16; ++n) {
                float dA = expf(delta * A[n]);
                h[n] = fmaf(dA, h[n], du * sm.Bs[dir][t][n]);
                y = fmaf(h[n], sm.Cs[dir][t][n], y);
            }
            sm.yscan[dir][t][d] = fmaf(u, dsd, y);   // + xs*Ds
        }
    }
    __syncthreads();

    // ---- phase 5: combine directions, gate with gelu(z)
    for (int idx = lt; idx < 512; idx += 128) {
        int t = idx >> 6;
        int d = idx & 63;
        float v = sm.yscan[0][t][d] + sm.yscan[1][7 - t][d];
        sm.ycomb[t][d] = v * geluf(sm.zz[t][d]);
    }
    __syncthreads();

    // ---- phase 6: y @ W_out, write pre-GN y, accumulate group stats
    for (int idx = lt; idx < 256; idx += 128) {
        int t  = idx >> 5;
        int gc = idx & 31;
        float acc = 0.f;
        for (int d = 0; d < 64; ++d)
            acc = fmaf(sm.ycomb[t][d], W_out[d * 32 + gc], acc);
        ws_y[(size_t)m * 256 + idx] = acc;
        int g = t >> 1;   // channel = t*32+gc, group = channel/64 = t/2
        atomicAdd(&sm.gsum[g], acc);
        atomicAdd(&sm.gsq[g], acc * acc);
    }
    __syncthreads();

    if (lt < 4) {
        int slot = blockIdx.x & (NSLOT - 1);
        int base = ((b * 4 + lt) * 2) * NSLOT + slot;
        atomicAdd(&stats[base],         (double)sm.gsum[lt]);
        atomicAdd(&stats[base + NSLOT], (double)sm.gsq[lt]);
    }
}

__global__ __launch_bounds__(256) void k2_norm(
    const float* __restrict__ x,
    const float* __restrict__ ws_y,
    const double* __restrict__ stats,
    const float* __restrict__ gn_w,
    const float* __restrict__ gn_b,
    float* __restrict__ out)
{
    __shared__ float tile[64 * 65];   // [ci][wi], +1 pad vs 64 to dodge banks
    __shared__ float s_mu, s_rs;
    const int bid = blockIdx.x;
    const int b   = bid >> 8;         // 256 blocks per b (64 h x 4 groups)
    const int rem = bid & 255;
    const int h   = rem >> 2;
    const int g   = rem & 3;
    const int c0  = g * 64;

    if (threadIdx.x == 0) {
        double s = 0.0, q = 0.0;
        int base = ((b * 4 + g) * 2) * NSLOT;
        for (int i = 0; i < NSLOT; ++i) { s += stats[base + i]; q += stats[base + NSLOT + i]; }
        const double N = 64.0 * 4096.0;
        double mu  = s / N;
        double var = q / N - mu * mu;   // population variance (jnp.var ddof=0)
        s_mu = (float)mu;
        s_rs = (float)(1.0 / sqrt(var + 1e-5));
    }
    __syncthreads();

    const int mbase = b * HWN + h * 64;
    for (int idx = threadIdx.x; idx < 4096; idx += 256) {
        int wi = idx >> 6;
        int ci = idx & 63;
        tile[ci * 65 + wi] = ws_y[(size_t)(mbase + wi) * 256 + c0 + ci];
    }
    __syncthreads();

    const float mu = s_mu, rs = s_rs;
    for (int idx = threadIdx.x; idx < 4096; idx += 256) {
        int ci = idx >> 6;
        int wi = idx & 63;
        int c  = c0 + ci;
        size_t o = ((size_t)(b * 256 + c)) * HWN + h * 64 + wi;
        out[o] = x[o] + (tile[ci * 65 + wi] - mu) * rs * gn_w[c] + gn_b[c];
    }
}

extern "C" void kernel_launch(void* const* d_in, const int* in_sizes, int n_in,
                              void* d_out, int out_size, void* d_ws, size_t ws_size,
                              hipStream_t stream) {
    (void)in_sizes; (void)n_in; (void)out_size; (void)ws_size;
    const float* x      = (const float*)d_in[0];
    const float* W_in   = (const float*)d_in[1];
    const float* W_x    = (const float*)d_in[2];
    const float* W_dt   = (const float*)d_in[3];
    const float* b_dt   = (const float*)d_in[4];
    const float* A_logs = (const float*)d_in[5];
    const float* Ds     = (const float*)d_in[6];
    const float* W_out  = (const float*)d_in[7];
    const float* gn_w   = (const float*)d_in[8];
    const float* gn_b   = (const float*)d_in[9];
    float* out = (float*)d_out;

    float*  ws_y  = (float*)d_ws;                                   // 16 MiB
    double* stats = (double*)((char*)d_ws + (size_t)M_TOT * 256 * 4);

    hipMemsetAsync(stats, 0, (size_t)BBN * 4 * 2 * NSLOT * sizeof(double), stream);
    k1_scan<<<M_TOT / 2, 256, 0, stream>>>(x, W_in, W_x, W_dt, b_dt, A_logs,
                                           Ds, W_out, ws_y, stats);
    k2_norm<<<BBN * 64 * 4, 256, 0, stream>>>(x, ws_y, stats, gn_w, gn_b, out);
}

// Round 3
// 306.289 us; speedup vs baseline: 1.1628x; 1.1628x over previous
//
#include <hip/hip_runtime.h>
#include <math.h>

// Problem constants: B=4, CH=256, H=W=64, TOK=8, GCN=32, PAD=256, DIN=64,
// DSTATE=16, DTR=2, GROUPS=4.
#define TOKN 8
#define GCNN 32
#define DINN 64
#define DST 16
#define CHN 256
#define HWN 4096      // H*W
#define BBN 4
#define M_TOT 16384   // B*H*W
#define NSLOT 64      // contention-spreading slots per (b,group) stat

__device__ __forceinline__ float softplus_fast(float v) {
    // logaddexp(v,0) = max(v,0) + log1p(exp(-|v|)); fast-math variant
    return fmaxf(v, 0.f) + __logf(1.f + __expf(-fabsf(v)));
}
__device__ __forceinline__ float geluf(float v) {
    return 0.5f * v * (1.f + erff(v * 0.70710678118654752f));
}

struct alignas(16) PixSmem {
    float xft[32][8];       // [k][t] transposed input tokens (1024 B)
    float xp[8][64];        // xz[...,:64]
    float zz[8][64];        // xz[...,64:]
    float dts[2][8][2];     // raw dt cols per direction
    float Bs[2][8][16];
    float Cs[2][8][16];
    float yscan[2][8][64];  // scan outputs (+ xs*Ds)
    float ycomb[8][64];     // (fwd + rev(bwd)) * gelu(z)
    float gsum[4];
    float gsq[4];
};

__global__ __launch_bounds__(256) void k1_scan(
    const float* __restrict__ x,
    const float* __restrict__ W_in,    // (32,128)
    const float* __restrict__ W_x,     // (64,34)
    const float* __restrict__ W_dt,    // (2,64)
    const float* __restrict__ b_dt,    // (64,)
    const float* __restrict__ A_logs,  // (64,16)
    const float* __restrict__ Ds,      // (64,)
    const float* __restrict__ W_out,   // (64,32)
    float* __restrict__ ws_y,          // (M,256) pre-GN output
    double* __restrict__ stats)        // (4,4,2,NSLOT)
{
    __shared__ PixSmem sm2[2];
    const int pix = threadIdx.x >> 7;
    const int lt  = threadIdx.x & 127;
    PixSmem& sm = sm2[pix];
    const int m  = blockIdx.x * 2 + pix;
    const int b  = m >> 12;
    const int hw = m & (HWN - 1);
    const float* xpix = x + (size_t)b * (CHN * HWN) + hw;

    // ---- phase 1: load 256 channels, store transposed [k][t]
    if (lt < 4)      sm.gsum[lt] = 0.f;
    else if (lt < 8) sm.gsq[lt - 4] = 0.f;
    for (int c = lt; c < 256; c += 128)
        sm.xft[c & 31][c >> 5] = xpix[(size_t)c * HWN];
    __syncthreads();

    // ---- phase 2: xz = xf @ W_in (thread owns output column lt of 128)
    {
        float acc[8];
        #pragma unroll
        for (int t = 0; t < 8; ++t) acc[t] = 0.f;
        #pragma unroll
        for (int k = 0; k < 32; ++k) {
            float wv = W_in[k * 128 + lt];
            float4 a0 = *reinterpret_cast<const float4*>(&sm.xft[k][0]);
            float4 a1 = *reinterpret_cast<const float4*>(&sm.xft[k][4]);
            acc[0] = fmaf(a0.x, wv, acc[0]);
            acc[1] = fmaf(a0.y, wv, acc[1]);
            acc[2] = fmaf(a0.z, wv, acc[2]);
            acc[3] = fmaf(a0.w, wv, acc[3]);
            acc[4] = fmaf(a1.x, wv, acc[4]);
            acc[5] = fmaf(a1.y, wv, acc[5]);
            acc[6] = fmaf(a1.z, wv, acc[6]);
            acc[7] = fmaf(a1.w, wv, acc[7]);
        }
        if (lt < 64) {
            #pragma unroll
            for (int t = 0; t < 8; ++t) sm.xp[t][lt] = acc[t];
        } else {
            #pragma unroll
            for (int t = 0; t < 8; ++t) sm.zz[t][lt - 64] = acc[t];
        }
    }
    __syncthreads();

    // ---- phase 3: x_dbl = xs @ W_x (544 outputs: 2 dir x 8 t x 34 cols)
    for (int idx = lt; idx < 544; idx += 128) {
        int dir = idx / 272;
        int r   = idx - dir * 272;
        int t   = r / 34;
        int col = r - t * 34;
        int ts  = dir ? (7 - t) : t;   // xs backward = token-reversed xp
        float acc = 0.f;
        #pragma unroll
        for (int k4 = 0; k4 < 16; ++k4) {
            float4 xv = *reinterpret_cast<const float4*>(&sm.xp[ts][k4 * 4]);
            acc = fmaf(xv.x, W_x[(k4 * 4 + 0) * 34 + col], acc);
            acc = fmaf(xv.y, W_x[(k4 * 4 + 1) * 34 + col], acc);
            acc = fmaf(xv.z, W_x[(k4 * 4 + 2) * 34 + col], acc);
            acc = fmaf(xv.w, W_x[(k4 * 4 + 3) * 34 + col], acc);
        }
        if (col < 2)        sm.dts[dir][t][col] = acc;
        else if (col < 18)  sm.Bs[dir][t][col - 2] = acc;
        else                sm.Cs[dir][t][col - 18] = acc;
    }
    __syncthreads();

    // ---- phase 4: selective scan. thread = (dir, d); 16-state in registers
    {
        const int dir = lt >> 6;
        const int d   = lt & 63;
        float A[16];
        #pragma unroll
        for (int n = 0; n < 16; ++n) A[n] = -__expf(A_logs[d * 16 + n]);
        const float w0  = W_dt[d];
        const float w1  = W_dt[64 + d];
        const float b2  = 2.f * b_dt[d];   // reference adds b_dt twice
        const float dsd = Ds[d];
        float h[16];
        #pragma unroll
        for (int n = 0; n < 16; ++n) h[n] = 0.f;
        #pragma unroll
        for (int t = 0; t < 8; ++t) {
            int ts = dir ? (7 - t) : t;
            float u = sm.xp[ts][d];
            float delta = softplus_fast(fmaf(sm.dts[dir][t][0], w0,
                                        fmaf(sm.dts[dir][t][1], w1, b2)));
            float du = delta * u;
            float y = 0.f;
            #pragma unroll
            for (int n = 0; n < 16; ++n) {
                float dA = __expf(delta * A[n]);
                h[n] = fmaf(dA, h[n], du * sm.Bs[dir][t][n]);
                y = fmaf(h[n], sm.Cs[dir][t][n], y);
            }
            sm.yscan[dir][t][d] = fmaf(u, dsd, y);   // + xs*Ds
        }
    }
    __syncthreads();

    // ---- phase 5: combine directions, gate with gelu(z)
    for (int idx = lt; idx < 512; idx += 128) {
        int t = idx >> 6;
        int d = idx & 63;
        float v = sm.yscan[0][t][d] + sm.yscan[1][7 - t][d];
        sm.ycomb[t][d] = v * geluf(sm.zz[t][d]);
    }
    __syncthreads();

    // ---- phase 6: y @ W_out, write pre-GN y, accumulate group stats
    for (int idx = lt; idx < 256; idx += 128) {
        int t  = idx >> 5;
        int gc = idx & 31;
        float acc = 0.f;
        #pragma unroll
        for (int d4 = 0; d4 < 16; ++d4) {
            float4 yv = *reinterpret_cast<const float4*>(&sm.ycomb[t][d4 * 4]);
            acc = fmaf(yv.x, W_out[(d4 * 4 + 0) * 32 + gc], acc);
            acc = fmaf(yv.y, W_out[(d4 * 4 + 1) * 32 + gc], acc);
            acc = fmaf(yv.z, W_out[(d4 * 4 + 2) * 32 + gc], acc);
            acc = fmaf(yv.w, W_out[(d4 * 4 + 3) * 32 + gc], acc);
        }
        ws_y[(size_t)m * 256 + idx] = acc;
        int g = t >> 1;   // channel = t*32+gc, group = channel/64 = t/2
        atomicAdd(&sm.gsum[g], acc);
        atomicAdd(&sm.gsq[g], acc * acc);
    }
    __syncthreads();

    if (lt < 4) {
        int slot = blockIdx.x & (NSLOT - 1);
        int base = ((b * 4 + lt) * 2) * NSLOT + slot;
        atomicAdd(&stats[base],         (double)sm.gsum[lt]);
        atomicAdd(&stats[base + NSLOT], (double)sm.gsq[lt]);
    }
}

__global__ __launch_bounds__(256) void k2_norm(
    const float* __restrict__ x,
    const float* __restrict__ ws_y,
    const double* __restrict__ stats,
    const float* __restrict__ gn_w,
    const float* __restrict__ gn_b,
    float* __restrict__ out)
{
    __shared__ float tile[64 * 65];
    __shared__ float s_mu, s_rs;
    const int bid = blockIdx.x;
    const int b   = bid >> 8;
    const int rem = bid & 255;
    const int h   = rem >> 2;
    const int g   = rem & 3;
    const int c0  = g * 64;

    if (threadIdx.x == 0) {
        double s = 0.0, q = 0.0;
        int base = ((b * 4 + g) * 2) * NSLOT;
        for (int i = 0; i < NSLOT; ++i) { s += stats[base + i]; q += stats[base + NSLOT + i]; }
        const double N = 64.0 * 4096.0;
        double mu  = s / N;
        double var = q / N - mu * mu;   // population variance
        s_mu = (float)mu;
        s_rs = (float)(1.0 / sqrt(var + 1e-5));
    }
    __syncthreads();

    const int mbase = b * HWN + h * 64;
    for (int idx = threadIdx.x; idx < 4096; idx += 256) {
        int wi = idx >> 6;
        int ci = idx & 63;
        tile[ci * 65 + wi] = ws_y[(size_t)(mbase + wi) * 256 + c0 + ci];
    }
    __syncthreads();

    const float mu = s_mu, rs = s_rs;
    for (int idx = threadIdx.x; idx < 4096; idx += 256) {
        int ci = idx >> 6;
        int wi = idx & 63;
        int c  = c0 + ci;
        size_t o = ((size_t)(b * 256 + c)) * HWN + h * 64 + wi;
        out[o] = x[o] + (tile[ci * 65 + wi] - mu) * rs * gn_w[c] + gn_b[c];
    }
}

extern "C" void kernel_launch(void* const* d_in, const int* in_sizes, int n_in,
                              void* d_out, int out_size, void* d_ws, size_t ws_size,
                              hipStream_t stream) {
    (void)in_sizes; (void)n_in; (void)out_size; (void)ws_size;
    const float* x      = (const float*)d_in[0];
    const float* W_in   = (const float*)d_in[1];
    const float* W_x    = (const float*)d_in[2];
    const float* W_dt   = (const float*)d_in[3];
    const float* b_dt   = (const float*)d_in[4];
    const float* A_logs = (const float*)d_in[5];
    const float* Ds     = (const float*)d_in[6];
    const float* W_out  = (const float*)d_in[7];
    const float* gn_w   = (const float*)d_in[8];
    const float* gn_b   = (const float*)d_in[9];
    float* out = (float*)d_out;

    float*  ws_y  = (float*)d_ws;                                   // 16 MiB
    double* stats = (double*)((char*)d_ws + (size_t)M_TOT * 256 * 4);

    hipMemsetAsync(stats, 0, (size_t)BBN * 4 * 2 * NSLOT * sizeof(double), stream);
    k1_scan<<<M_TOT / 2, 256, 0, stream>>>(x, W_in, W_x, W_dt, b_dt, A_logs,
                                           Ds, W_out, ws_y, stats);
    k2_norm<<<BBN * 64 * 4, 256, 0, stream>>>(x, ws_y, stats, gn_w, gn_b, out);
}